// Round 14
// baseline (77.210 us; speedup 1.0000x reference)
//
#include <hip/hip_runtime.h>
#include <hip/hip_bf16.h>
#include <stdint.h>
#include <stddef.h>

// DecorrLoss: grad = 0.5*mean_C(offdiag) + 0.5*diag(mean(x^2)-1), corr_loss, whit_loss
// x: f32 [8,4096,1024] -> [M=32768][D=1024]
//   pass1: f32 -> fp8 e4m3 (HW cvt_pk) TILE-LINEAR transposed XT (R11, verified)
//   gemm : 256x256 triangle tiles (10), 8 waves, MX-scaled fp8 MFMA 16x16x128,
//          split-K S=24 XCD-chunked, BK=128B, 2-deep counted vmcnt(8) +
//          4-PHASE compute split (m201 template): per phase {ds_read subtile,
//          barrier, lgkmcnt(0)+sched_barrier, setprio+8 MFMA, barrier};
//          STAGE in phase 3 under Q3's MFMAs. bf16-packed C.
//   epi  : FUSED for 256^2 tiles: sum S partials -> upper write (+diag fixup) +
//          LDS-transposed mirror of the lower block.
//   fin1/fin2: deterministic scalar losses

#define D_DIM 1024
#define M_ROWS 32768
#define BK 128
#define NKBS (M_ROWS / BK)         // 256 K-blocks of 128
#define NT2 10                     // 4*5/2 triangle tiles at 256^2
#define CPT_U32 32768              // u32 per packed 256^2 tile
#define CT_STRIDE 2097152          // bytes per 64-row group in tiled xt

typedef __attribute__((ext_vector_type(4))) float f32x4;
typedef __attribute__((ext_vector_type(4))) int i32x4;
typedef __attribute__((ext_vector_type(8))) int i32x8;

__device__ inline unsigned short f2bf(float f) {
  unsigned int b = __float_as_uint(f);
  return (unsigned short)((b + 0x7fffu + ((b >> 16) & 1u)) >> 16);  // RNE
}

__device__ inline void gload_lds16(const void* g, void* l) {
  __builtin_amdgcn_global_load_lds(
      (const __attribute__((address_space(1))) void*)g,
      (__attribute__((address_space(3))) void*)l,
      16, 0, 0);
}

__device__ inline float dppsum16(float v) {
  v += __uint_as_float((unsigned)__builtin_amdgcn_update_dpp(
      0, (int)__float_as_uint(v), 0xB1, 0xF, 0xF, true));
  v += __uint_as_float((unsigned)__builtin_amdgcn_update_dpp(
      0, (int)__float_as_uint(v), 0x4E, 0xF, 0xF, true));
  v += __uint_as_float((unsigned)__builtin_amdgcn_update_dpp(
      0, (int)__float_as_uint(v), 0x141, 0xF, 0xF, true));
  v += __uint_as_float((unsigned)__builtin_amdgcn_update_dpp(
      0, (int)__float_as_uint(v), 0x140, 0xF, 0xF, true));
  return v;
}

// ---------------- pass 1 (R11, verified) ----------------
__global__ __launch_bounds__(256) void k_pass1(const float* __restrict__ x,
                                               unsigned char* __restrict__ xt,
                                               float* __restrict__ rssp,
                                               float* __restrict__ rs4p) {
  __shared__ unsigned int sh32[16 * 68];
  const int bid = blockIdx.x;
  const int mt = bid & 511;
  const int m0 = mt * 64;
  const int ct = bid >> 9;
  const int c0 = ct * 64;
  const int t = (int)threadIdx.x;
  const int q = t >> 4;
  const int cg = t & 15;

  unsigned int p[4];
  float ss[4], s4[4];
#pragma unroll
  for (int mi = 0; mi < 4; ++mi) {
    const float4 v = *(const float4*)(x + (size_t)(m0 + q * 4 + mi) * D_DIM + c0 + cg * 4);
    const float q0 = v.x * v.x, q1 = v.y * v.y, q2 = v.z * v.z, q3 = v.w * v.w;
    ss[mi] = q0 + q1 + q2 + q3;
    s4[mi] = q0 * q0 + q1 * q1 + q2 * q2 + q3 * q3;
    unsigned int u = (unsigned int)__builtin_amdgcn_cvt_pk_fp8_f32(v.x, v.y, 0, false);
    p[mi] = (unsigned int)__builtin_amdgcn_cvt_pk_fp8_f32(v.z, v.w, (int)u, true);
  }
#pragma unroll
  for (int mi = 0; mi < 4; ++mi) {
    ss[mi] = dppsum16(ss[mi]);
    s4[mi] = dppsum16(s4[mi]);
  }
  if (cg == 0) {
#pragma unroll
    for (int mi = 0; mi < 4; ++mi) {
      rssp[ct * M_ROWS + m0 + q * 4 + mi] = ss[mi];
      rs4p[ct * M_ROWS + m0 + q * 4 + mi] = s4[mi];
    }
  }

  const unsigned int t01l = __builtin_amdgcn_perm(p[1], p[0], 0x05010400u);
  const unsigned int t01h = __builtin_amdgcn_perm(p[1], p[0], 0x07030602u);
  const unsigned int t23l = __builtin_amdgcn_perm(p[3], p[2], 0x05010400u);
  const unsigned int t23h = __builtin_amdgcn_perm(p[3], p[2], 0x07030602u);
  uint4 w;
  w.x = __builtin_amdgcn_perm(t23l, t01l, 0x05040100u);
  w.y = __builtin_amdgcn_perm(t23l, t01l, 0x07060302u);
  w.z = __builtin_amdgcn_perm(t23h, t01h, 0x05040100u);
  w.w = __builtin_amdgcn_perm(t23h, t01h, 0x07060302u);
  *(uint4*)&sh32[q * 68 + cg * 4] = w;
  __syncthreads();

  const int c = t >> 2, mh = t & 3;
  uint4 o;
  o.x = sh32[(mh * 4 + 0) * 68 + c];
  o.y = sh32[(mh * 4 + 1) * 68 + c];
  o.z = sh32[(mh * 4 + 2) * 68 + c];
  o.w = sh32[(mh * 4 + 3) * 68 + c];
  *(uint4*)(xt + (size_t)ct * CT_STRIDE + ((size_t)mt << 12) + t * 16) = o;
}

// ---------------- gemm: 256^2 MX-fp8, counted vmcnt + 4-phase compute split --------
// grid: S * 10 blocks, 512 threads (8 waves: 2M x 4N of 128x64)
// xt tile-linear: byte(row,k) = (row>>6)*CT_STRIDE + (k>>6)*4096 + (row&63)*64 + (k&63)
__global__ __launch_bounds__(512, 2) void k_gemm(const unsigned char* __restrict__ xt,
                                                 unsigned int* __restrict__ cpart,
                                                 int S, int swz) {
  __shared__ unsigned char As[2][32768];
  __shared__ unsigned char Bs[2][32768];
  const int bid = (int)blockIdx.x;
  int s, tidx;
  if (swz) {
    const int xcd = bid & 7;
    tidx = (bid >> 3) % NT2;
    s = (bid / (8 * NT2)) * 8 + xcd;
  } else {
    s = bid / NT2;
    tidx = bid - s * NT2;
  }
  int rem = tidx, ti = 0;
  while (rem >= 4 - ti) { rem -= 4 - ti; ++ti; }
  const int tj = ti + rem;

  const int t = (int)threadIdx.x;
  const int l = t & 63, w = t >> 6;
  const int wr2 = w >> 2, wc4 = w & 3;       // wave: rows wr2*128, cols wc4*64
  const int r = l & 15, g = l >> 4;

  f32x4 acc[8][4];
#pragma unroll
  for (int mi = 0; mi < 8; ++mi)
#pragma unroll
    for (int ni = 0; ni < 4; ++ni) acc[mi][ni] = (f32x4){0.f, 0.f, 0.f, 0.f};

  // staging: 512 threads cover 256 rows x 128B per matrix per buffer (4 x 16B each).
  // LDS dest [j*8192 + t*16] = row (j*64 + t>>3), slot (t&7); source slot ^ (row&7).
  const int srow = t >> 3;                   // 0..63
  const int slot = (t & 7) ^ (srow & 7);
  const int slterm = (slot >> 2) * 4096 + (slot & 3) * 16;
  const unsigned char* pa[4];
  const unsigned char* pb[4];
#pragma unroll
  for (int j = 0; j < 4; ++j) {
    pa[j] = xt + (size_t)(ti * 4 + j) * CT_STRIDE + srow * 64 + slterm;
    pb[j] = xt + (size_t)(tj * 4 + j) * CT_STRIDE + srow * 64 + slterm;
  }

  // diag tiles stage B redundantly (uniform 8 loads -> constant vmcnt counts)
#define STAGE(B, K) do { \
    const size_t koff = (size_t)(K) << 6; \
    _Pragma("unroll") \
    for (int j = 0; j < 4; ++j) { \
      gload_lds16(pa[j] + koff, &As[B][j * 8192 + t * 16]); \
      gload_lds16(pb[j] + koff, &Bs[B][j * 8192 + t * 16]); \
    } \
  } while (0)

  const int swb = r & 7;
  const int oA0 = (((2 * g + 0) ^ swb) << 4);
  const int oA1 = (((2 * g + 1) ^ swb) << 4);
  const int arow = (wr2 * 128 + r) * 128;
  const int brow = (wc4 * 64 + r) * 128;

#define RD_A(mi) do { \
    const i32x4 lo_ = *(const i32x4*)(Ab + arow + (mi) * 2048 + oA0); \
    const i32x4 hi_ = *(const i32x4*)(Ab + arow + (mi) * 2048 + oA1); \
    a8[mi] = (i32x8){lo_[0], lo_[1], lo_[2], lo_[3], hi_[0], hi_[1], hi_[2], hi_[3]}; \
  } while (0)
#define RD_B(ni) do { \
    const i32x4 lo_ = *(const i32x4*)(Bb + brow + (ni) * 2048 + oA0); \
    const i32x4 hi_ = *(const i32x4*)(Bb + brow + (ni) * 2048 + oA1); \
    b8[ni] = (i32x8){lo_[0], lo_[1], lo_[2], lo_[3], hi_[0], hi_[1], hi_[2], hi_[3]}; \
  } while (0)
#define MM(mi, ni) \
    acc[mi][ni] = __builtin_amdgcn_mfma_scale_f32_16x16x128_f8f6f4( \
        a8[mi], b8[ni], acc[mi][ni], 0, 0, 0, 0x7F7F7F7Fu, 0, 0x7F7F7F7Fu)
#define PH_SYNC() do { \
    __builtin_amdgcn_s_barrier(); \
    asm volatile("s_waitcnt lgkmcnt(0)" ::: "memory"); \
    __builtin_amdgcn_sched_barrier(0); \
  } while (0)

  // K partition: NKBS chunks of BK over S splits
  const int kq = NKBS / S, kr = NKBS - kq * S;
  const int kb0 = s * kq + (s < kr ? s : kr);
  const int nkb = kq + (s < kr ? 1 : 0);
  int kb = kb0 * BK;

  STAGE(0, kb);
  STAGE(1, kb + BK);

  for (int it = 0; it < nkb; ++it) {
    if (it == nkb - 1)
      asm volatile("s_waitcnt vmcnt(0)" ::: "memory");
    else
      asm volatile("s_waitcnt vmcnt(8)" ::: "memory");
    __builtin_amdgcn_s_barrier();

    const unsigned char* Ab = As[it & 1];
    const unsigned char* Bb = Bs[it & 1];
    i32x8 a8[8], b8[4];

    // ---- phase 0: reads a8[0..3], b8[0..1]; MFMA Q0 = mi0-3 x ni0-1
    RD_B(0); RD_B(1); RD_A(0); RD_A(1); RD_A(2); RD_A(3);
    PH_SYNC();
    __builtin_amdgcn_s_setprio(1);
    MM(0, 0); MM(0, 1); MM(1, 0); MM(1, 1);
    MM(2, 0); MM(2, 1); MM(3, 0); MM(3, 1);
    __builtin_amdgcn_s_setprio(0);
    __builtin_amdgcn_s_barrier();

    // ---- phase 1: reads a8[4..7]; MFMA Q1 = mi4-7 x ni0-1
    RD_A(4); RD_A(5); RD_A(6); RD_A(7);
    PH_SYNC();
    __builtin_amdgcn_s_setprio(1);
    MM(4, 0); MM(4, 1); MM(5, 0); MM(5, 1);
    MM(6, 0); MM(6, 1); MM(7, 0); MM(7, 1);
    __builtin_amdgcn_s_setprio(0);
    __builtin_amdgcn_s_barrier();

    // ---- phase 2: reads b8[2..3]; MFMA Q2 = mi0-3 x ni2-3
    RD_B(2); RD_B(3);
    PH_SYNC();
    __builtin_amdgcn_s_setprio(1);
    MM(0, 2); MM(0, 3); MM(1, 2); MM(1, 3);
    MM(2, 2); MM(2, 3); MM(3, 2); MM(3, 3);
    __builtin_amdgcn_s_setprio(0);
    __builtin_amdgcn_s_barrier();

    // ---- phase 3: all reads of buf[it&1] are done (Q2's barrier) -> WAR-safe
    // to re-stage this buffer for tile it+2; loads fly under Q3's MFMAs.
    if (it + 2 < nkb) STAGE(it & 1, kb + 2 * BK);
    __builtin_amdgcn_s_setprio(1);
    MM(4, 2); MM(4, 3); MM(5, 2); MM(5, 3);
    MM(6, 2); MM(6, 3); MM(7, 2); MM(7, 3);
    __builtin_amdgcn_s_setprio(0);
    kb += BK;
  }
#undef STAGE
#undef RD_A
#undef RD_B
#undef MM
#undef PH_SYNC

  // C/D: col = lane&15, row = (lane>>4)*4 + reg. Pack row-pairs as bf16.
  unsigned int* cp = cpart + ((size_t)s * NT2 + tidx) * CPT_U32;
#pragma unroll
  for (int mi = 0; mi < 8; ++mi) {
    const int rowb = wr2 * 128 + mi * 16 + g * 4;   // even
#pragma unroll
    for (int ni = 0; ni < 4; ++ni) {
      const int col = wc4 * 64 + ni * 16 + r;
      const unsigned int w0 = (unsigned int)f2bf(acc[mi][ni][0]) |
                              ((unsigned int)f2bf(acc[mi][ni][1]) << 16);
      const unsigned int w1 = (unsigned int)f2bf(acc[mi][ni][2]) |
                              ((unsigned int)f2bf(acc[mi][ni][3]) << 16);
      cp[(size_t)((rowb >> 1) + 0) * 256 + col] = w0;
      cp[(size_t)((rowb >> 1) + 1) * 256 + col] = w1;
    }
  }
}

// ---------------- fused epi for 256^2 tiles ----------------
// grid 10 tiles x 32 chunks = 320 blocks, 256 threads.
__global__ __launch_bounds__(256) void k_epi(const unsigned int* __restrict__ cpart,
                                             float* __restrict__ out, int S) {
  __shared__ float smir[8][260];
  const int b = (int)blockIdx.x;
  const int tile = b >> 5, chunk = b & 31;
  int rem = tile, ti = 0;
  while (rem >= 4 - ti) { rem -= 4 - ti; ++ti; }
  const int tj = ti + rem;
  const int t = (int)threadIdx.x;
  const int qq = (chunk * 256 + t) * 4;   // u32 index within tile
  const int rpl = t >> 6;                 // rowpair-local 0..3
  const int c = (t & 63) * 4;

  const unsigned int* cp = cpart + (size_t)tile * CPT_U32 + qq;
  const size_t st = (size_t)NT2 * CPT_U32;
  float lo0 = 0.f, lo1 = 0.f, lo2 = 0.f, lo3 = 0.f;
  float hi0 = 0.f, hi1 = 0.f, hi2 = 0.f, hi3 = 0.f;
  for (int s = 0; s < S; ++s) {
    const uint4 v = *(const uint4*)(cp + (size_t)s * st);
    lo0 += __uint_as_float(v.x << 16); hi0 += __uint_as_float(v.x & 0xFFFF0000u);
    lo1 += __uint_as_float(v.y << 16); hi1 += __uint_as_float(v.y & 0xFFFF0000u);
    lo2 += __uint_as_float(v.z << 16); hi2 += __uint_as_float(v.z & 0xFFFF0000u);
    lo3 += __uint_as_float(v.w << 16); hi3 += __uint_as_float(v.w & 0xFFFF0000u);
  }

  const float sc = 0.5f / (float)M_ROWS;
  f32x4 lo = (f32x4){lo0 * sc, lo1 * sc, lo2 * sc, lo3 * sc};
  f32x4 hi = (f32x4){hi0 * sc, hi1 * sc, hi2 * sc, hi3 * sc};

  const int gi = ti * 256 + chunk * 8 + 2 * rpl;
  const int gj = tj * 256 + c;
  if (ti == tj) {   // diag fixup
#pragma unroll
    for (int kk = 0; kk < 4; ++kk) {
      if (gi == gj + kk) lo[kk] -= 0.5f;
      if (gi + 1 == gj + kk) hi[kk] -= 0.5f;
    }
  }
  *(f32x4*)(out + (size_t)gi * D_DIM + gj) = lo;
  *(f32x4*)(out + (size_t)(gi + 1) * D_DIM + gj) = hi;

  if (ti != tj) {   // mirror lower block via LDS transpose
    const int jr = 2 * rpl;
    *(f32x4*)&smir[jr][c] = lo;
    *(f32x4*)&smir[jr + 1][c] = hi;
    __syncthreads();
    const int cc = t;                      // 0..255
    f32x4 m0v, m1v;
    m0v[0] = smir[0][cc]; m0v[1] = smir[1][cc];
    m0v[2] = smir[2][cc]; m0v[3] = smir[3][cc];
    m1v[0] = smir[4][cc]; m1v[1] = smir[5][cc];
    m1v[2] = smir[6][cc]; m1v[3] = smir[7][cc];
    float* ob = out + (size_t)(tj * 256 + cc) * D_DIM + ti * 256 + chunk * 8;
    *(f32x4*)(ob + 0) = m0v;
    *(f32x4*)(ob + 4) = m1v;
  }
}

// ---------------- fin1 / fin2 (unchanged) ----------------
__global__ __launch_bounds__(256) void k_fin1(const float* __restrict__ rssp,
                                              const float* __restrict__ rs4p,
                                              float* __restrict__ scp) {
  __shared__ float sm[3][4];
  const int t = (int)threadIdx.x;
  const int m = (int)blockIdx.x * 256 + t;
  float a = 0.f, b = 0.f;
#pragma unroll
  for (int ct = 0; ct < 16; ++ct) {
    a += rssp[ct * M_ROWS + m];
    b += rs4p[ct * M_ROWS + m];
  }
  float corr = a * a - b;
#pragma unroll
  for (int off = 32; off; off >>= 1) {
    corr += __shfl_down(corr, off);
    a += __shfl_down(a, off);
    b += __shfl_down(b, off);
  }
  const int wv = t >> 6;
  if ((t & 63) == 0) { sm[0][wv] = corr; sm[1][wv] = a; sm[2][wv] = b; }
  __syncthreads();
  if (t == 0) {
    float c4 = 0.f, a4 = 0.f, b4 = 0.f;
#pragma unroll
    for (int i = 0; i < 4; ++i) { c4 += sm[0][i]; a4 += sm[1][i]; b4 += sm[2][i]; }
    scp[(int)blockIdx.x * 4 + 0] = c4;
    scp[(int)blockIdx.x * 4 + 1] = a4;
    scp[(int)blockIdx.x * 4 + 2] = b4;
  }
}

__global__ __launch_bounds__(128) void k_fin2(const float* __restrict__ scp,
                                              float* __restrict__ out) {
  __shared__ float sm[3][2];
  const int t = (int)threadIdx.x;
  float c = scp[t * 4 + 0], a = scp[t * 4 + 1], b = scp[t * 4 + 2];
#pragma unroll
  for (int off = 32; off; off >>= 1) {
    c += __shfl_down(c, off);
    a += __shfl_down(a, off);
    b += __shfl_down(b, off);
  }
  const int wv = t >> 6;
  if ((t & 63) == 0) { sm[0][wv] = c; sm[1][wv] = a; sm[2][wv] = b; }
  __syncthreads();
  if (t == 0) {
    const double ct = (double)sm[0][0] + (double)sm[0][1];
    const double st = (double)sm[1][0] + (double)sm[1][1];
    const double qt = (double)sm[2][0] + (double)sm[2][1];
    const double N = (double)M_ROWS * (double)D_DIM;
    out[1048576] = (float)(ct / (double)M_ROWS / ((double)D_DIM * (double)D_DIM));
    out[1048577] = (float)((qt - 2.0 * st + N) / N);
  }
}

extern "C" void kernel_launch(void* const* d_in, const int* in_sizes, int n_in,
                              void* d_out, int out_size, void* d_ws, size_t ws_size,
                              hipStream_t stream) {
  (void)in_sizes; (void)n_in; (void)out_size;
  const float* x = (const float*)d_in[0];
  float* out = (float*)d_out;
  char* ws = (char*)d_ws;

  // ws layout:
  unsigned char* xt = (unsigned char*)ws;                   // 33,554,432 B (fp8, tiled)
  float* rssp = (float*)(ws + 33554432);                    //  2,097,152 B
  float* rs4p = (float*)(ws + 35651584);                    //  2,097,152 B
  float* scp  = (float*)(ws + 37748736);                    //      4,096 B
  unsigned int* cpart = (unsigned int*)(ws + 37752832);     //  S * 1,310,720 B
  const size_t base = 37752832;
  size_t avail = (ws_size > base) ? (ws_size - base) : 0;
  int S = (int)(avail / (sizeof(unsigned int) * NT2 * CPT_U32));
  if (S > 24) S = 24;                 // 240 blocks ~ 1/CU (LDS 128KB), XCD-chunked
  int swz = 0;
  if (S >= 8) { S &= ~7; swz = 1; }
  if (S < 1) S = 1;

  k_pass1<<<8192, 256, 0, stream>>>(x, xt, rssp, rs4p);
  k_gemm<<<NT2 * S, 512, 0, stream>>>(xt, cpart, S, swz);
  k_epi<<<NT2 * 32, 256, 0, stream>>>(cpart, out, S);
  k_fin1<<<128, 256, 0, stream>>>(rssp, rs4p, scp);
  k_fin2<<<1, 128, 0, stream>>>(scp, out);
}

// Round 15
// 76.019 us; speedup vs baseline: 1.0157x; 1.0157x over previous
//
#include <hip/hip_runtime.h>
#include <hip/hip_bf16.h>
#include <stdint.h>
#include <stddef.h>

// DecorrLoss: grad = 0.5*mean_C(offdiag) + 0.5*diag(mean(x^2)-1), corr_loss, whit_loss
// x: f32 [8,4096,1024] -> [M=32768][D=1024]
//   pass1: f32 -> fp8 e4m3 (HW cvt_pk) transposed XT, PAGE-COHERENT: ct-inner
//          block decode (concurrent blocks read the same 64 rows at adjacent
//          256B windows) + [mt][ct] tile layout (write stream globally
//          sequential: xt[bid*4096 + t*16]). DPP stats, v_perm 4x4 transpose.
//   gemm : R12 (best): 256x256 triangle tiles (10), 8 waves, MX-scaled fp8 MFMA
//          16x16x128, split-K S=24 XCD-chunked, BK=128B, 2-deep counted vmcnt(8),
//          stage-under-MFMA, setprio. bf16-packed C. (Addressing remapped to the
//          [mt][ct] xt layout: per-K-step staging reads one contiguous 16KB run
//          per 64-row group.)
//   epi  : FUSED: sum S partials -> upper write (+diag fixup) + LDS-transposed
//          mirror of the lower block.
//   fin1/fin2: deterministic scalar losses

#define D_DIM 1024
#define M_ROWS 32768
#define BK 128
#define NKBS (M_ROWS / BK)         // 256 K-blocks of 128
#define NT2 10                     // 4*5/2 triangle tiles at 256^2
#define CPT_U32 32768              // u32 per packed 256^2 tile

typedef __attribute__((ext_vector_type(4))) float f32x4;
typedef __attribute__((ext_vector_type(4))) int i32x4;
typedef __attribute__((ext_vector_type(8))) int i32x8;

__device__ inline unsigned short f2bf(float f) {
  unsigned int b = __float_as_uint(f);
  return (unsigned short)((b + 0x7fffu + ((b >> 16) & 1u)) >> 16);  // RNE
}

__device__ inline void gload_lds16(const void* g, void* l) {
  __builtin_amdgcn_global_load_lds(
      (const __attribute__((address_space(1))) void*)g,
      (__attribute__((address_space(3))) void*)l,
      16, 0, 0);
}

__device__ inline float dppsum16(float v) {
  v += __uint_as_float((unsigned)__builtin_amdgcn_update_dpp(
      0, (int)__float_as_uint(v), 0xB1, 0xF, 0xF, true));   // xor1 quad_perm
  v += __uint_as_float((unsigned)__builtin_amdgcn_update_dpp(
      0, (int)__float_as_uint(v), 0x4E, 0xF, 0xF, true));   // xor2 quad_perm
  v += __uint_as_float((unsigned)__builtin_amdgcn_update_dpp(
      0, (int)__float_as_uint(v), 0x141, 0xF, 0xF, true));  // xor4 row_half_mirror
  v += __uint_as_float((unsigned)__builtin_amdgcn_update_dpp(
      0, (int)__float_as_uint(v), 0x140, 0xF, 0xF, true));  // xor8 row_mirror
  return v;
}

// ---------------- pass 1: page-coherent transpose + fp8 + row stats ----------------
// grid: 8192 blocks, 256 threads. DECODE: ct = bid&15 (inner), mt = bid>>4.
// Consecutive (concurrent) blocks read the SAME 64 rows at adjacent 256B windows.
// xt layout [mt][ct]: block writes xt[bid*4096 + t*16] -> globally sequential.
__global__ __launch_bounds__(256) void k_pass1(const float* __restrict__ x,
                                               unsigned char* __restrict__ xt,
                                               float* __restrict__ rssp,
                                               float* __restrict__ rs4p) {
  __shared__ unsigned int sh32[16 * 68];
  const int bid = blockIdx.x;
  const int ct = bid & 15;            // c-tile (inner -> page-coherent reads)
  const int mt = bid >> 4;
  const int m0 = mt * 64;
  const int c0 = ct * 64;
  const int t = (int)threadIdx.x;
  const int q = t >> 4;               // m-group (4 rows); 16-lane-aligned for DPP
  const int cg = t & 15;              // col group (4 cols)

  unsigned int p[4];
  float ss[4], s4[4];
#pragma unroll
  for (int mi = 0; mi < 4; ++mi) {
    const float4 v = *(const float4*)(x + (size_t)(m0 + q * 4 + mi) * D_DIM + c0 + cg * 4);
    const float q0 = v.x * v.x, q1 = v.y * v.y, q2 = v.z * v.z, q3 = v.w * v.w;
    ss[mi] = q0 + q1 + q2 + q3;
    s4[mi] = q0 * q0 + q1 * q1 + q2 * q2 + q3 * q3;
    unsigned int u = (unsigned int)__builtin_amdgcn_cvt_pk_fp8_f32(v.x, v.y, 0, false);
    p[mi] = (unsigned int)__builtin_amdgcn_cvt_pk_fp8_f32(v.z, v.w, (int)u, true);
  }
#pragma unroll
  for (int mi = 0; mi < 4; ++mi) {
    ss[mi] = dppsum16(ss[mi]);
    s4[mi] = dppsum16(s4[mi]);
  }
  if (cg == 0) {
#pragma unroll
    for (int mi = 0; mi < 4; ++mi) {
      rssp[ct * M_ROWS + m0 + q * 4 + mi] = ss[mi];
      rs4p[ct * M_ROWS + m0 + q * 4 + mi] = s4[mi];
    }
  }

  // 4x4 byte transpose in registers
  const unsigned int t01l = __builtin_amdgcn_perm(p[1], p[0], 0x05010400u);
  const unsigned int t01h = __builtin_amdgcn_perm(p[1], p[0], 0x07030602u);
  const unsigned int t23l = __builtin_amdgcn_perm(p[3], p[2], 0x05010400u);
  const unsigned int t23h = __builtin_amdgcn_perm(p[3], p[2], 0x07030602u);
  uint4 w;
  w.x = __builtin_amdgcn_perm(t23l, t01l, 0x05040100u);
  w.y = __builtin_amdgcn_perm(t23l, t01l, 0x07060302u);
  w.z = __builtin_amdgcn_perm(t23h, t01h, 0x05040100u);
  w.w = __builtin_amdgcn_perm(t23h, t01h, 0x07060302u);
  *(uint4*)&sh32[q * 68 + cg * 4] = w;
  __syncthreads();

  // write-out: one contiguous 4KB per block (tile = 64 c-rows x 64 m, c-major)
  const int c = t >> 2, mh = t & 3;
  uint4 o;
  o.x = sh32[(mh * 4 + 0) * 68 + c];
  o.y = sh32[(mh * 4 + 1) * 68 + c];
  o.z = sh32[(mh * 4 + 2) * 68 + c];
  o.w = sh32[(mh * 4 + 3) * 68 + c];
  *(uint4*)(xt + ((size_t)bid << 12) + t * 16) = o;
}

// ---------------- gemm: 256^2 MX-fp8, counted-vmcnt 2-deep (R12 schedule) ----------
// grid: S * 10 blocks, 512 threads (8 waves: 2M x 4N of 128x64)
// xt [mt][ct]: byte(row,k) = ((k>>6)*16 + (row>>6))*4096 + (row&63)*64 + (k&63)
__global__ __launch_bounds__(512, 2) void k_gemm(const unsigned char* __restrict__ xt,
                                                 unsigned int* __restrict__ cpart,
                                                 int S, int swz) {
  __shared__ unsigned char As[2][32768];
  __shared__ unsigned char Bs[2][32768];
  const int bid = (int)blockIdx.x;
  int s, tidx;
  if (swz) {
    const int xcd = bid & 7;
    tidx = (bid >> 3) % NT2;
    s = (bid / (8 * NT2)) * 8 + xcd;
  } else {
    s = bid / NT2;
    tidx = bid - s * NT2;
  }
  int rem = tidx, ti = 0;
  while (rem >= 4 - ti) { rem -= 4 - ti; ++ti; }
  const int tj = ti + rem;

  const int t = (int)threadIdx.x;
  const int l = t & 63, w = t >> 6;
  const int wr2 = w >> 2, wc4 = w & 3;       // wave: rows wr2*128, cols wc4*64
  const int r = l & 15, g = l >> 4;

  f32x4 acc[8][4];
#pragma unroll
  for (int mi = 0; mi < 8; ++mi)
#pragma unroll
    for (int ni = 0; ni < 4; ++ni) acc[mi][ni] = (f32x4){0.f, 0.f, 0.f, 0.f};

  // staging: LDS dest [j*8192 + t*16] = row (j*64 + t>>3), slot (t&7);
  // source slot ^ (row&7). k = kb + slot*16 -> addr terms:
  //   (slot>>2)*65536 + (slot&3)*16 (k within 128B) ; koff = (K>>6)*65536 = K<<10
  const int srow = t >> 3;                   // 0..63
  const int slot = (t & 7) ^ (srow & 7);
  const int slterm = (slot >> 2) * 65536 + (slot & 3) * 16;
  const unsigned char* pa[4];
  const unsigned char* pb[4];
#pragma unroll
  for (int j = 0; j < 4; ++j) {
    pa[j] = xt + (size_t)(ti * 4 + j) * 4096 + srow * 64 + slterm;
    pb[j] = xt + (size_t)(tj * 4 + j) * 4096 + srow * 64 + slterm;
  }

  // diag tiles stage B redundantly (uniform 8 loads -> constant vmcnt counts)
#define STAGE(B, K) do { \
    const size_t koff = (size_t)(K) << 10; \
    _Pragma("unroll") \
    for (int j = 0; j < 4; ++j) { \
      gload_lds16(pa[j] + koff, &As[B][j * 8192 + t * 16]); \
      gload_lds16(pb[j] + koff, &Bs[B][j * 8192 + t * 16]); \
    } \
  } while (0)

  const int swb = r & 7;
  const int oA0 = (((2 * g + 0) ^ swb) << 4);
  const int oA1 = (((2 * g + 1) ^ swb) << 4);
  const int arow = (wr2 * 128 + r) * 128;
  const int brow = (wc4 * 64 + r) * 128;

  // K partition: NKBS chunks of BK over S splits
  const int kq = NKBS / S, kr = NKBS - kq * S;
  const int kb0 = s * kq + (s < kr ? s : kr);
  const int nkb = kq + (s < kr ? 1 : 0);
  int kb = kb0 * BK;

  STAGE(0, kb);
  STAGE(1, kb + BK);

  for (int it = 0; it < nkb; ++it) {
    if (it == nkb - 1)
      asm volatile("s_waitcnt vmcnt(0)" ::: "memory");
    else
      asm volatile("s_waitcnt vmcnt(8)" ::: "memory");
    __builtin_amdgcn_s_barrier();

    const unsigned char* Ab = As[it & 1];
    const unsigned char* Bb = Bs[it & 1];
    i32x8 a8[8], b8[4];
#pragma unroll
    for (int mi = 0; mi < 8; ++mi) {
      const i32x4 lo = *(const i32x4*)(Ab + arow + mi * 2048 + oA0);
      const i32x4 hi = *(const i32x4*)(Ab + arow + mi * 2048 + oA1);
      a8[mi] = (i32x8){lo[0], lo[1], lo[2], lo[3], hi[0], hi[1], hi[2], hi[3]};
    }
#pragma unroll
    for (int ni = 0; ni < 4; ++ni) {
      const i32x4 lo = *(const i32x4*)(Bb + brow + ni * 2048 + oA0);
      const i32x4 hi = *(const i32x4*)(Bb + brow + ni * 2048 + oA1);
      b8[ni] = (i32x8){lo[0], lo[1], lo[2], lo[3], hi[0], hi[1], hi[2], hi[3]};
    }
    asm volatile("s_waitcnt lgkmcnt(0)" ::: "memory");
    __builtin_amdgcn_s_barrier();

    if (it + 2 < nkb) STAGE(it & 1, kb + 2 * BK);  // flight hides under MFMAs

    __builtin_amdgcn_s_setprio(1);
#pragma unroll
    for (int ni = 0; ni < 4; ++ni)
#pragma unroll
      for (int mi = 0; mi < 8; ++mi)
        acc[mi][ni] = __builtin_amdgcn_mfma_scale_f32_16x16x128_f8f6f4(
            a8[mi], b8[ni], acc[mi][ni], 0, 0, 0, 0x7F7F7F7Fu, 0, 0x7F7F7F7Fu);
    __builtin_amdgcn_s_setprio(0);
    kb += BK;
  }
#undef STAGE

  // C/D: col = lane&15, row = (lane>>4)*4 + reg. Pack row-pairs as bf16.
  unsigned int* cp = cpart + ((size_t)s * NT2 + tidx) * CPT_U32;
#pragma unroll
  for (int mi = 0; mi < 8; ++mi) {
    const int rowb = wr2 * 128 + mi * 16 + g * 4;   // even
#pragma unroll
    for (int ni = 0; ni < 4; ++ni) {
      const int col = wc4 * 64 + ni * 16 + r;
      const unsigned int w0 = (unsigned int)f2bf(acc[mi][ni][0]) |
                              ((unsigned int)f2bf(acc[mi][ni][1]) << 16);
      const unsigned int w1 = (unsigned int)f2bf(acc[mi][ni][2]) |
                              ((unsigned int)f2bf(acc[mi][ni][3]) << 16);
      cp[(size_t)((rowb >> 1) + 0) * 256 + col] = w0;
      cp[(size_t)((rowb >> 1) + 1) * 256 + col] = w1;
    }
  }
}

// ---------------- fused epi for 256^2 tiles ----------------
// grid 10 tiles x 32 chunks = 320 blocks, 256 threads.
__global__ __launch_bounds__(256) void k_epi(const unsigned int* __restrict__ cpart,
                                             float* __restrict__ out, int S) {
  __shared__ float smir[8][260];
  const int b = (int)blockIdx.x;
  const int tile = b >> 5, chunk = b & 31;
  int rem = tile, ti = 0;
  while (rem >= 4 - ti) { rem -= 4 - ti; ++ti; }
  const int tj = ti + rem;
  const int t = (int)threadIdx.x;
  const int qq = (chunk * 256 + t) * 4;   // u32 index within tile
  const int rpl = t >> 6;                 // rowpair-local 0..3
  const int c = (t & 63) * 4;

  const unsigned int* cp = cpart + (size_t)tile * CPT_U32 + qq;
  const size_t st = (size_t)NT2 * CPT_U32;
  float lo0 = 0.f, lo1 = 0.f, lo2 = 0.f, lo3 = 0.f;
  float hi0 = 0.f, hi1 = 0.f, hi2 = 0.f, hi3 = 0.f;
  for (int s = 0; s < S; ++s) {
    const uint4 v = *(const uint4*)(cp + (size_t)s * st);
    lo0 += __uint_as_float(v.x << 16); hi0 += __uint_as_float(v.x & 0xFFFF0000u);
    lo1 += __uint_as_float(v.y << 16); hi1 += __uint_as_float(v.y & 0xFFFF0000u);
    lo2 += __uint_as_float(v.z << 16); hi2 += __uint_as_float(v.z & 0xFFFF0000u);
    lo3 += __uint_as_float(v.w << 16); hi3 += __uint_as_float(v.w & 0xFFFF0000u);
  }

  const float sc = 0.5f / (float)M_ROWS;
  f32x4 lo = (f32x4){lo0 * sc, lo1 * sc, lo2 * sc, lo3 * sc};
  f32x4 hi = (f32x4){hi0 * sc, hi1 * sc, hi2 * sc, hi3 * sc};

  const int gi = ti * 256 + chunk * 8 + 2 * rpl;
  const int gj = tj * 256 + c;
  if (ti == tj) {   // diag fixup
#pragma unroll
    for (int kk = 0; kk < 4; ++kk) {
      if (gi == gj + kk) lo[kk] -= 0.5f;
      if (gi + 1 == gj + kk) hi[kk] -= 0.5f;
    }
  }
  *(f32x4*)(out + (size_t)gi * D_DIM + gj) = lo;
  *(f32x4*)(out + (size_t)(gi + 1) * D_DIM + gj) = hi;

  if (ti != tj) {   // mirror lower block via LDS transpose
    const int jr = 2 * rpl;
    *(f32x4*)&smir[jr][c] = lo;
    *(f32x4*)&smir[jr + 1][c] = hi;
    __syncthreads();
    const int cc = t;                      // 0..255
    f32x4 m0v, m1v;
    m0v[0] = smir[0][cc]; m0v[1] = smir[1][cc];
    m0v[2] = smir[2][cc]; m0v[3] = smir[3][cc];
    m1v[0] = smir[4][cc]; m1v[1] = smir[5][cc];
    m1v[2] = smir[6][cc]; m1v[3] = smir[7][cc];
    float* ob = out + (size_t)(tj * 256 + cc) * D_DIM + ti * 256 + chunk * 8;
    *(f32x4*)(ob + 0) = m0v;
    *(f32x4*)(ob + 4) = m1v;
  }
}

// ---------------- fin1 / fin2 (unchanged) ----------------
__global__ __launch_bounds__(256) void k_fin1(const float* __restrict__ rssp,
                                              const float* __restrict__ rs4p,
                                              float* __restrict__ scp) {
  __shared__ float sm[3][4];
  const int t = (int)threadIdx.x;
  const int m = (int)blockIdx.x * 256 + t;
  float a = 0.f, b = 0.f;
#pragma unroll
  for (int ct = 0; ct < 16; ++ct) {
    a += rssp[ct * M_ROWS + m];
    b += rs4p[ct * M_ROWS + m];
  }
  float corr = a * a - b;
#pragma unroll
  for (int off = 32; off; off >>= 1) {
    corr += __shfl_down(corr, off);
    a += __shfl_down(a, off);
    b += __shfl_down(b, off);
  }
  const int wv = t >> 6;
  if ((t & 63) == 0) { sm[0][wv] = corr; sm[1][wv] = a; sm[2][wv] = b; }
  __syncthreads();
  if (t == 0) {
    float c4 = 0.f, a4 = 0.f, b4 = 0.f;
#pragma unroll
    for (int i = 0; i < 4; ++i) { c4 += sm[0][i]; a4 += sm[1][i]; b4 += sm[2][i]; }
    scp[(int)blockIdx.x * 4 + 0] = c4;
    scp[(int)blockIdx.x * 4 + 1] = a4;
    scp[(int)blockIdx.x * 4 + 2] = b4;
  }
}

__global__ __launch_bounds__(128) void k_fin2(const float* __restrict__ scp,
                                              float* __restrict__ out) {
  __shared__ float sm[3][2];
  const int t = (int)threadIdx.x;
  float c = scp[t * 4 + 0], a = scp[t * 4 + 1], b = scp[t * 4 + 2];
#pragma unroll
  for (int off = 32; off; off >>= 1) {
    c += __shfl_down(c, off);
    a += __shfl_down(a, off);
    b += __shfl_down(b, off);
  }
  const int wv = t >> 6;
  if ((t & 63) == 0) { sm[0][wv] = c; sm[1][wv] = a; sm[2][wv] = b; }
  __syncthreads();
  if (t == 0) {
    const double ct = (double)sm[0][0] + (double)sm[0][1];
    const double st = (double)sm[1][0] + (double)sm[1][1];
    const double qt = (double)sm[2][0] + (double)sm[2][1];
    const double N = (double)M_ROWS * (double)D_DIM;
    out[1048576] = (float)(ct / (double)M_ROWS / ((double)D_DIM * (double)D_DIM));
    out[1048577] = (float)((qt - 2.0 * st + N) / N);
  }
}

extern "C" void kernel_launch(void* const* d_in, const int* in_sizes, int n_in,
                              void* d_out, int out_size, void* d_ws, size_t ws_size,
                              hipStream_t stream) {
  (void)in_sizes; (void)n_in; (void)out_size;
  const float* x = (const float*)d_in[0];
  float* out = (float*)d_out;
  char* ws = (char*)d_ws;

  // ws layout:
  unsigned char* xt = (unsigned char*)ws;                   // 33,554,432 B (fp8, [mt][ct])
  float* rssp = (float*)(ws + 33554432);                    //  2,097,152 B
  float* rs4p = (float*)(ws + 35651584);                    //  2,097,152 B
  float* scp  = (float*)(ws + 37748736);                    //      4,096 B
  unsigned int* cpart = (unsigned int*)(ws + 37752832);     //  S * 1,310,720 B
  const size_t base = 37752832;
  size_t avail = (ws_size > base) ? (ws_size - base) : 0;
  int S = (int)(avail / (sizeof(unsigned int) * NT2 * CPT_U32));
  if (S > 24) S = 24;                 // 240 blocks ~ 1/CU (LDS 128KB), XCD-chunked
  int swz = 0;
  if (S >= 8) { S &= ~7; swz = 1; }
  if (S < 1) S = 1;

  k_pass1<<<8192, 256, 0, stream>>>(x, xt, rssp, rs4p);
  k_gemm<<<NT2 * S, 512, 0, stream>>>(xt, cpart, S, swz);
  k_epi<<<NT2 * 32, 256, 0, stream>>>(cpart, out, S);
  k_fin1<<<128, 256, 0, stream>>>(rssp, rs4p, scp);
  k_fin2<<<1, 128, 0, stream>>>(scp, out);
}

// Round 16
// 70.935 us; speedup vs baseline: 1.0885x; 1.0717x over previous
//
#include <hip/hip_runtime.h>
#include <hip/hip_bf16.h>
#include <stdint.h>
#include <stddef.h>

// DecorrLoss: grad = 0.5*mean_C(offdiag) + 0.5*diag(mean(x^2)-1), corr_loss, whit_loss
// x: f32 [8,4096,1024] -> [M=32768][D=1024]
//   pass1: f32 -> fp8 e4m3 (HW cvt_pk) transposed XT, [mt][ct] tile layout,
//          sequential 4KB-per-block writes, DPP stats, v_perm 4x4 transpose.
//   gemm : 256x256 triangle tiles (10), 8 waves, MX-scaled fp8 MFMA 16x16x128,
//          split-K S=24 XCD-chunked, BK=128B, 2-deep counted vmcnt (8 offdiag /
//          4 diag -- diag tiles stage A only and read B-fragments from As),
//          stage-under-MFMA, setprio. bf16-packed C.
//   epi  : FUSED epi + fin1 in one launch (448 blocks): blocks 0-319 sum S
//          partials -> upper write (+diag fixup) + LDS-transposed lower mirror;
//          blocks 320-447 reduce row stats -> scp.
//   fin2 : final scalars (1 block).

#define D_DIM 1024
#define M_ROWS 32768
#define BK 128
#define NKBS (M_ROWS / BK)         // 256 K-blocks of 128
#define NT2 10                     // 4*5/2 triangle tiles at 256^2
#define CPT_U32 32768              // u32 per packed 256^2 tile

typedef __attribute__((ext_vector_type(4))) float f32x4;
typedef __attribute__((ext_vector_type(4))) int i32x4;
typedef __attribute__((ext_vector_type(8))) int i32x8;

__device__ inline unsigned short f2bf(float f) {
  unsigned int b = __float_as_uint(f);
  return (unsigned short)((b + 0x7fffu + ((b >> 16) & 1u)) >> 16);  // RNE
}

__device__ inline void gload_lds16(const void* g, void* l) {
  __builtin_amdgcn_global_load_lds(
      (const __attribute__((address_space(1))) void*)g,
      (__attribute__((address_space(3))) void*)l,
      16, 0, 0);
}

__device__ inline float dppsum16(float v) {
  v += __uint_as_float((unsigned)__builtin_amdgcn_update_dpp(
      0, (int)__float_as_uint(v), 0xB1, 0xF, 0xF, true));   // xor1 quad_perm
  v += __uint_as_float((unsigned)__builtin_amdgcn_update_dpp(
      0, (int)__float_as_uint(v), 0x4E, 0xF, 0xF, true));   // xor2 quad_perm
  v += __uint_as_float((unsigned)__builtin_amdgcn_update_dpp(
      0, (int)__float_as_uint(v), 0x141, 0xF, 0xF, true));  // xor4 row_half_mirror
  v += __uint_as_float((unsigned)__builtin_amdgcn_update_dpp(
      0, (int)__float_as_uint(v), 0x140, 0xF, 0xF, true));  // xor8 row_mirror
  return v;
}

// ---------------- pass 1: transpose + fp8 + row stats ----------------
// grid: 8192 blocks, 256 threads. ct = bid&15, mt = bid>>4; xt [mt][ct] tiles.
__global__ __launch_bounds__(256) void k_pass1(const float* __restrict__ x,
                                               unsigned char* __restrict__ xt,
                                               float* __restrict__ rssp,
                                               float* __restrict__ rs4p) {
  __shared__ unsigned int sh32[16 * 68];
  const int bid = blockIdx.x;
  const int ct = bid & 15;
  const int mt = bid >> 4;
  const int m0 = mt * 64;
  const int c0 = ct * 64;
  const int t = (int)threadIdx.x;
  const int q = t >> 4;               // m-group (4 rows); 16-lane-aligned for DPP
  const int cg = t & 15;              // col group (4 cols)

  unsigned int p[4];
  float ss[4], s4[4];
#pragma unroll
  for (int mi = 0; mi < 4; ++mi) {
    const float4 v = *(const float4*)(x + (size_t)(m0 + q * 4 + mi) * D_DIM + c0 + cg * 4);
    const float q0 = v.x * v.x, q1 = v.y * v.y, q2 = v.z * v.z, q3 = v.w * v.w;
    ss[mi] = q0 + q1 + q2 + q3;
    s4[mi] = q0 * q0 + q1 * q1 + q2 * q2 + q3 * q3;
    unsigned int u = (unsigned int)__builtin_amdgcn_cvt_pk_fp8_f32(v.x, v.y, 0, false);
    p[mi] = (unsigned int)__builtin_amdgcn_cvt_pk_fp8_f32(v.z, v.w, (int)u, true);
  }
#pragma unroll
  for (int mi = 0; mi < 4; ++mi) {
    ss[mi] = dppsum16(ss[mi]);
    s4[mi] = dppsum16(s4[mi]);
  }
  if (cg == 0) {
#pragma unroll
    for (int mi = 0; mi < 4; ++mi) {
      rssp[ct * M_ROWS + m0 + q * 4 + mi] = ss[mi];
      rs4p[ct * M_ROWS + m0 + q * 4 + mi] = s4[mi];
    }
  }

  // 4x4 byte transpose in registers
  const unsigned int t01l = __builtin_amdgcn_perm(p[1], p[0], 0x05010400u);
  const unsigned int t01h = __builtin_amdgcn_perm(p[1], p[0], 0x07030602u);
  const unsigned int t23l = __builtin_amdgcn_perm(p[3], p[2], 0x05010400u);
  const unsigned int t23h = __builtin_amdgcn_perm(p[3], p[2], 0x07030602u);
  uint4 w;
  w.x = __builtin_amdgcn_perm(t23l, t01l, 0x05040100u);
  w.y = __builtin_amdgcn_perm(t23l, t01l, 0x07060302u);
  w.z = __builtin_amdgcn_perm(t23h, t01h, 0x05040100u);
  w.w = __builtin_amdgcn_perm(t23h, t01h, 0x07060302u);
  *(uint4*)&sh32[q * 68 + cg * 4] = w;
  __syncthreads();

  // write-out: one contiguous 4KB per block (tile = 64 c-rows x 64 m, c-major)
  const int c = t >> 2, mh = t & 3;
  uint4 o;
  o.x = sh32[(mh * 4 + 0) * 68 + c];
  o.y = sh32[(mh * 4 + 1) * 68 + c];
  o.z = sh32[(mh * 4 + 2) * 68 + c];
  o.w = sh32[(mh * 4 + 3) * 68 + c];
  *(uint4*)(xt + ((size_t)bid << 12) + t * 16) = o;
}

// ---------------- gemm: 256^2 MX-fp8, counted-vmcnt 2-deep, diag stages A only ----
// grid: S * 10 blocks, 512 threads (8 waves: 2M x 4N of 128x64)
// xt [mt][ct]: byte(row,k) = ((k>>6)*16 + (row>>6))*4096 + (row&63)*64 + (k&63)
__global__ __launch_bounds__(512, 2) void k_gemm(const unsigned char* __restrict__ xt,
                                                 unsigned int* __restrict__ cpart,
                                                 int S, int swz) {
  __shared__ unsigned char As[2][32768];
  __shared__ unsigned char Bs[2][32768];
  const int bid = (int)blockIdx.x;
  int s, tidx;
  if (swz) {
    const int xcd = bid & 7;
    tidx = (bid >> 3) % NT2;
    s = (bid / (8 * NT2)) * 8 + xcd;
  } else {
    s = bid / NT2;
    tidx = bid - s * NT2;
  }
  int rem = tidx, ti = 0;
  while (rem >= 4 - ti) { rem -= 4 - ti; ++ti; }
  const int tj = ti + rem;
  const bool diag = (ti == tj);

  const int t = (int)threadIdx.x;
  const int l = t & 63, w = t >> 6;
  const int wr2 = w >> 2, wc4 = w & 3;       // wave: rows wr2*128, cols wc4*64
  const int r = l & 15, g = l >> 4;

  f32x4 acc[8][4];
#pragma unroll
  for (int mi = 0; mi < 8; ++mi)
#pragma unroll
    for (int ni = 0; ni < 4; ++ni) acc[mi][ni] = (f32x4){0.f, 0.f, 0.f, 0.f};

  const int srow = t >> 3;                   // 0..63
  const int slot = (t & 7) ^ (srow & 7);
  const int slterm = (slot >> 2) * 65536 + (slot & 3) * 16;
  const unsigned char* pa[4];
  const unsigned char* pb[4];
#pragma unroll
  for (int j = 0; j < 4; ++j) {
    pa[j] = xt + (size_t)(ti * 4 + j) * 4096 + srow * 64 + slterm;
    pb[j] = xt + (size_t)(tj * 4 + j) * 4096 + srow * 64 + slterm;
  }

  // diag: stage A only (4 loads); offdiag: A+B (8 loads)
#define STAGE(B, K) do { \
    const size_t koff = (size_t)(K) << 10; \
    _Pragma("unroll") \
    for (int j = 0; j < 4; ++j) { \
      gload_lds16(pa[j] + koff, &As[B][j * 8192 + t * 16]); \
      if (!diag) gload_lds16(pb[j] + koff, &Bs[B][j * 8192 + t * 16]); \
    } \
  } while (0)

  const int swb = r & 7;
  const int oA0 = (((2 * g + 0) ^ swb) << 4);
  const int oA1 = (((2 * g + 1) ^ swb) << 4);
  const int arow = (wr2 * 128 + r) * 128;
  const int brow = (wc4 * 64 + r) * 128;

  // K partition: NKBS chunks of BK over S splits
  const int kq = NKBS / S, kr = NKBS - kq * S;
  const int kb0 = s * kq + (s < kr ? s : kr);
  const int nkb = kq + (s < kr ? 1 : 0);
  int kb = kb0 * BK;

  STAGE(0, kb);
  STAGE(1, kb + BK);

  for (int it = 0; it < nkb; ++it) {
    // steady state: stage(it) must land; stage(it+1)'s loads stay in flight.
    if (it == nkb - 1)
      asm volatile("s_waitcnt vmcnt(0)" ::: "memory");
    else if (diag)
      asm volatile("s_waitcnt vmcnt(4)" ::: "memory");
    else
      asm volatile("s_waitcnt vmcnt(8)" ::: "memory");
    __builtin_amdgcn_s_barrier();

    const unsigned char* Ab = As[it & 1];
    const unsigned char* Bb = diag ? As[it & 1] : Bs[it & 1];
    i32x8 a8[8], b8[4];
#pragma unroll
    for (int mi = 0; mi < 8; ++mi) {
      const i32x4 lo = *(const i32x4*)(Ab + arow + mi * 2048 + oA0);
      const i32x4 hi = *(const i32x4*)(Ab + arow + mi * 2048 + oA1);
      a8[mi] = (i32x8){lo[0], lo[1], lo[2], lo[3], hi[0], hi[1], hi[2], hi[3]};
    }
#pragma unroll
    for (int ni = 0; ni < 4; ++ni) {
      const i32x4 lo = *(const i32x4*)(Bb + brow + ni * 2048 + oA0);
      const i32x4 hi = *(const i32x4*)(Bb + brow + ni * 2048 + oA1);
      b8[ni] = (i32x8){lo[0], lo[1], lo[2], lo[3], hi[0], hi[1], hi[2], hi[3]};
    }
    asm volatile("s_waitcnt lgkmcnt(0)" ::: "memory");
    __builtin_amdgcn_s_barrier();

    if (it + 2 < nkb) STAGE(it & 1, kb + 2 * BK);  // flight hides under MFMAs

    __builtin_amdgcn_s_setprio(1);
#pragma unroll
    for (int ni = 0; ni < 4; ++ni)
#pragma unroll
      for (int mi = 0; mi < 8; ++mi)
        acc[mi][ni] = __builtin_amdgcn_mfma_scale_f32_16x16x128_f8f6f4(
            a8[mi], b8[ni], acc[mi][ni], 0, 0, 0, 0x7F7F7F7Fu, 0, 0x7F7F7F7Fu);
    __builtin_amdgcn_s_setprio(0);
    kb += BK;
  }
#undef STAGE

  // C/D: col = lane&15, row = (lane>>4)*4 + reg. Pack row-pairs as bf16.
  unsigned int* cp = cpart + ((size_t)s * NT2 + tidx) * CPT_U32;
#pragma unroll
  for (int mi = 0; mi < 8; ++mi) {
    const int rowb = wr2 * 128 + mi * 16 + g * 4;   // even
#pragma unroll
    for (int ni = 0; ni < 4; ++ni) {
      const int col = wc4 * 64 + ni * 16 + r;
      const unsigned int w0 = (unsigned int)f2bf(acc[mi][ni][0]) |
                              ((unsigned int)f2bf(acc[mi][ni][1]) << 16);
      const unsigned int w1 = (unsigned int)f2bf(acc[mi][ni][2]) |
                              ((unsigned int)f2bf(acc[mi][ni][3]) << 16);
      cp[(size_t)((rowb >> 1) + 0) * 256 + col] = w0;
      cp[(size_t)((rowb >> 1) + 1) * 256 + col] = w1;
    }
  }
}

// ---------------- fused epi + fin1: 448 blocks, 256 threads ----------------
// blocks 0..319: grad assembly (tile = b>>5, chunk = b&31)
// blocks 320..447: row-stat reduction -> scp[(b-320)*4 ..]
__global__ __launch_bounds__(256) void k_epi(const unsigned int* __restrict__ cpart,
                                             const float* __restrict__ rssp,
                                             const float* __restrict__ rs4p,
                                             float* __restrict__ scp,
                                             float* __restrict__ out, int S) {
  __shared__ float smir[8][260];
  const int b = (int)blockIdx.x;
  const int t = (int)threadIdx.x;

  if (b >= NT2 * 32) {               // ---- fin1 role ----
    const int fb = b - NT2 * 32;     // 0..127
    const int m = fb * 256 + t;
    float a = 0.f, bb = 0.f;
#pragma unroll
    for (int ct = 0; ct < 16; ++ct) {
      a += rssp[ct * M_ROWS + m];
      bb += rs4p[ct * M_ROWS + m];
    }
    float corr = a * a - bb;
#pragma unroll
    for (int off = 32; off; off >>= 1) {
      corr += __shfl_down(corr, off);
      a += __shfl_down(a, off);
      bb += __shfl_down(bb, off);
    }
    const int wv = t >> 6;
    if ((t & 63) == 0) { smir[0][wv] = corr; smir[1][wv] = a; smir[2][wv] = bb; }
    __syncthreads();
    if (t == 0) {
      float c4 = 0.f, a4 = 0.f, b4 = 0.f;
#pragma unroll
      for (int i = 0; i < 4; ++i) { c4 += smir[0][i]; a4 += smir[1][i]; b4 += smir[2][i]; }
      scp[fb * 4 + 0] = c4;
      scp[fb * 4 + 1] = a4;
      scp[fb * 4 + 2] = b4;
    }
    return;
  }

  // ---- epi role ----
  const int tile = b >> 5, chunk = b & 31;
  int rem = tile, ti = 0;
  while (rem >= 4 - ti) { rem -= 4 - ti; ++ti; }
  const int tj = ti + rem;
  const int qq = (chunk * 256 + t) * 4;   // u32 index within tile
  const int rpl = t >> 6;                 // rowpair-local 0..3
  const int c = (t & 63) * 4;

  const unsigned int* cp = cpart + (size_t)tile * CPT_U32 + qq;
  const size_t st = (size_t)NT2 * CPT_U32;
  float lo0 = 0.f, lo1 = 0.f, lo2 = 0.f, lo3 = 0.f;
  float hi0 = 0.f, hi1 = 0.f, hi2 = 0.f, hi3 = 0.f;
  for (int s = 0; s < S; ++s) {
    const uint4 v = *(const uint4*)(cp + (size_t)s * st);
    lo0 += __uint_as_float(v.x << 16); hi0 += __uint_as_float(v.x & 0xFFFF0000u);
    lo1 += __uint_as_float(v.y << 16); hi1 += __uint_as_float(v.y & 0xFFFF0000u);
    lo2 += __uint_as_float(v.z << 16); hi2 += __uint_as_float(v.z & 0xFFFF0000u);
    lo3 += __uint_as_float(v.w << 16); hi3 += __uint_as_float(v.w & 0xFFFF0000u);
  }

  const float sc = 0.5f / (float)M_ROWS;
  f32x4 lo = (f32x4){lo0 * sc, lo1 * sc, lo2 * sc, lo3 * sc};
  f32x4 hi = (f32x4){hi0 * sc, hi1 * sc, hi2 * sc, hi3 * sc};

  const int gi = ti * 256 + chunk * 8 + 2 * rpl;
  const int gj = tj * 256 + c;
  if (ti == tj) {   // diag fixup
#pragma unroll
    for (int kk = 0; kk < 4; ++kk) {
      if (gi == gj + kk) lo[kk] -= 0.5f;
      if (gi + 1 == gj + kk) hi[kk] -= 0.5f;
    }
  }
  *(f32x4*)(out + (size_t)gi * D_DIM + gj) = lo;
  *(f32x4*)(out + (size_t)(gi + 1) * D_DIM + gj) = hi;

  if (ti != tj) {   // mirror lower block via LDS transpose
    const int jr = 2 * rpl;
    *(f32x4*)&smir[jr][c] = lo;
    *(f32x4*)&smir[jr + 1][c] = hi;
    __syncthreads();
    const int cc = t;                      // 0..255
    f32x4 m0v, m1v;
    m0v[0] = smir[0][cc]; m0v[1] = smir[1][cc];
    m0v[2] = smir[2][cc]; m0v[3] = smir[3][cc];
    m1v[0] = smir[4][cc]; m1v[1] = smir[5][cc];
    m1v[2] = smir[6][cc]; m1v[3] = smir[7][cc];
    float* ob = out + (size_t)(tj * 256 + cc) * D_DIM + ti * 256 + chunk * 8;
    *(f32x4*)(ob + 0) = m0v;
    *(f32x4*)(ob + 4) = m1v;
  }
}

// ---------------- fin2: final scalars ----------------
__global__ __launch_bounds__(128) void k_fin2(const float* __restrict__ scp,
                                              float* __restrict__ out) {
  __shared__ float sm[3][2];
  const int t = (int)threadIdx.x;
  float c = scp[t * 4 + 0], a = scp[t * 4 + 1], b = scp[t * 4 + 2];
#pragma unroll
  for (int off = 32; off; off >>= 1) {
    c += __shfl_down(c, off);
    a += __shfl_down(a, off);
    b += __shfl_down(b, off);
  }
  const int wv = t >> 6;
  if ((t & 63) == 0) { sm[0][wv] = c; sm[1][wv] = a; sm[2][wv] = b; }
  __syncthreads();
  if (t == 0) {
    const double ct = (double)sm[0][0] + (double)sm[0][1];
    const double st = (double)sm[1][0] + (double)sm[1][1];
    const double qt = (double)sm[2][0] + (double)sm[2][1];
    const double N = (double)M_ROWS * (double)D_DIM;
    out[1048576] = (float)(ct / (double)M_ROWS / ((double)D_DIM * (double)D_DIM));
    out[1048577] = (float)((qt - 2.0 * st + N) / N);
  }
}

extern "C" void kernel_launch(void* const* d_in, const int* in_sizes, int n_in,
                              void* d_out, int out_size, void* d_ws, size_t ws_size,
                              hipStream_t stream) {
  (void)in_sizes; (void)n_in; (void)out_size;
  const float* x = (const float*)d_in[0];
  float* out = (float*)d_out;
  char* ws = (char*)d_ws;

  // ws layout:
  unsigned char* xt = (unsigned char*)ws;                   // 33,554,432 B (fp8, [mt][ct])
  float* rssp = (float*)(ws + 33554432);                    //  2,097,152 B
  float* rs4p = (float*)(ws + 35651584);                    //  2,097,152 B
  float* scp  = (float*)(ws + 37748736);                    //      4,096 B
  unsigned int* cpart = (unsigned int*)(ws + 37752832);     //  S * 1,310,720 B
  const size_t base = 37752832;
  size_t avail = (ws_size > base) ? (ws_size - base) : 0;
  int S = (int)(avail / (sizeof(unsigned int) * NT2 * CPT_U32));
  if (S > 24) S = 24;                 // 240 blocks ~ 1/CU (LDS 128KB), XCD-chunked
  int swz = 0;
  if (S >= 8) { S &= ~7; swz = 1; }
  if (S < 1) S = 1;

  k_pass1<<<8192, 256, 0, stream>>>(x, xt, rssp, rs4p);
  k_gemm<<<NT2 * S, 512, 0, stream>>>(xt, cpart, S, swz);
  k_epi<<<NT2 * 32 + 128, 256, 0, stream>>>(cpart, rssp, rs4p, scp, out, S);
  k_fin2<<<1, 128, 0, stream>>>(scp, out);
}